// Round 3
// baseline (308.112 us; speedup 1.0000x reference)
//
#include <hip/hip_runtime.h>
#include <stdint.h>

#define NB 64
#define NT 512
#define NH 768
#define NS 128
#define NM (NB*NS)   // 8192 rows

typedef _Float16 half8 __attribute__((ext_vector_type(8)));
typedef _Float16 half4 __attribute__((ext_vector_type(4)));
typedef __attribute__((ext_vector_type(4))) float f32x4;

__device__ __forceinline__ float gelu_exact(float x) {
  return 0.5f * x * (1.0f + erff(x * 0.70710678118654752440f));
}

// async global->LDS, 16B per lane; LDS dest is wave-uniform base (HW adds lane*16)
__device__ __forceinline__ void gll16(const void* g, void* l) {
  __builtin_amdgcn_global_load_lds(
      (__attribute__((address_space(1))) unsigned int*)g,
      (__attribute__((address_space(3))) unsigned int*)l,
      16, 0, 0);
}

// ---------------------------------------------------------------------------
// Weight prep: w[k][n] f32 -> W[w][n][k] f16 single, pre-swizzled (k ^ ((n&7)<<3))
// ---------------------------------------------------------------------------
__global__ void prep_w_kernel(const float* __restrict__ w1, const float* __restrict__ w2,
                              _Float16* __restrict__ W) {
  int id = blockIdx.x * 256 + threadIdx.x;   // 2*96*768 total
  int n  = id % NH;
  int t  = id / NH;
  int kc = t % 96;
  int w  = t / 96;
  const float* src = w ? w2 : w1;
  int k0 = kc * 8;
  half8 h;
#pragma unroll
  for (int i = 0; i < 8; ++i)
    h[i] = (_Float16)src[(size_t)(k0 + i) * NH + n];   // coalesced across n
  *(half8*)&W[(size_t)w * NH * NH + (size_t)n * NH + (size_t)(k0 ^ ((n & 7) << 3))] = h;
}

// ---------------------------------------------------------------------------
// Pool pass 1: streaming segment sums with atomic flush.
// grid (16 token-chunks, 64 batches), 192 threads (one float4-column each).
// Each hidden element is read exactly once, float4-coalesced.
// ---------------------------------------------------------------------------
__global__ void pool_sum_kernel(const float* __restrict__ hidden, const int* __restrict__ sid,
                                float* __restrict__ pooled) {
  __shared__ int s_sid[32];
  const int b = blockIdx.y, tc = blockIdx.x;
  const int t0 = tc * 32;
  if (threadIdx.x < 32) s_sid[threadIdx.x] = sid[b * NT + t0 + threadIdx.x];
  __syncthreads();
  const float* hb = hidden + (size_t)b * NT * NH + (size_t)t0 * NH;
  const int c4 = threadIdx.x;        // 0..191
  f32x4 acc = {0.f, 0.f, 0.f, 0.f};
  int cur = s_sid[0];
  for (int t = 0; t < 32; ++t) {
    int s = s_sid[t];
    if (s != cur) {                   // block-uniform (same t for all threads)
      float* dst = pooled + ((size_t)b * NS + cur) * NH + c4 * 4;
#pragma unroll
      for (int j = 0; j < 4; ++j) atomicAdd(dst + j, acc[j]);
      acc = (f32x4){0.f, 0.f, 0.f, 0.f};
      cur = s;
    }
    f32x4 v = *(const f32x4*)(hb + (size_t)t * NH + c4 * 4);
    acc += v;
  }
  float* dst = pooled + ((size_t)b * NS + cur) * NH + c4 * 4;
#pragma unroll
  for (int j = 0; j < 4; ++j) atomicAdd(dst + j, acc[j]);
}

// ---------------------------------------------------------------------------
// Pool pass 2: divide by count, f16 hi/lo split, swizzled store.
// ---------------------------------------------------------------------------
__global__ void convert_kernel(const float* __restrict__ pooled, const int* __restrict__ sid,
                               _Float16* __restrict__ Ahi, _Float16* __restrict__ Alo) {
  const int m = blockIdx.x;          // b*128 + s
  const int b = m >> 7, s = m & 127;
  const int* row = sid + b * NT;
  int lo = 0, hi = NT;
  while (lo < hi) { int mid = (lo + hi) >> 1; if (row[mid] < s) lo = mid + 1; else hi = mid; }
  const int e0 = lo;
  hi = NT;
  while (lo < hi) { int mid = (lo + hi) >> 1; if (row[mid] < s + 1) lo = mid + 1; else hi = mid; }
  const int cnt = lo - e0;
  const float inv = 1.0f / fmaxf((float)cnt, 1.0f);
  const int xorv = (m & 7) << 3;
  const int c = threadIdx.x * 4;     // 192 threads, float4 each
  f32x4 v = *(const f32x4*)(pooled + (size_t)m * NH + c);
  half4 h, l;
#pragma unroll
  for (int j = 0; j < 4; ++j) {
    float x = v[j] * inv;
    h[j] = (_Float16)x;
    l[j] = (_Float16)(x - (float)h[j]);
  }
  const size_t off = (size_t)m * NH + (size_t)(c ^ xorv);   // xor acts on bits 3..5: 4-aligned stays contiguous
  *(half4*)&Ahi[off] = h;
  *(half4*)&Alo[off] = l;
}

__global__ void finish_kernel(const float* __restrict__ part, const float* __restrict__ b3,
                              float* __restrict__ out) {
  int i = blockIdx.x * 256 + threadIdx.x;
  float s = b3[0];
#pragma unroll
  for (int j = 0; j < 12; ++j) s += part[(size_t)j * NM + i];
  out[i] = 1.0f / (1.0f + expf(-s));
}

// ---------------------------------------------------------------------------
// f16x2 GEMM, 128x128 tile, BK=64, 4 waves (2x2), 16x16x32 f16 MFMA.
// A: [M][768] swizzled f16 hi/lo.  W: [N][K] swizzled f16 single.
// EPI==0: C = gelu(A@W^T + bias) -> f16 hi/lo swizzled store
// EPI==1: per-row dot(gelu(..), w3) -> part[(nb*2+wc)][row]
//         (wc=0 and wc=1 waves cover different column halves -> DISTINCT slots;
//          R2 bug: both wrote part[nb][row], losing half the dot product)
// ---------------------------------------------------------------------------
template <int EPI>
__global__ __launch_bounds__(256, 3)
void gemm_kernel(const _Float16* __restrict__ Ahi, const _Float16* __restrict__ Alo,
                 const _Float16* __restrict__ W, const float* __restrict__ bias,
                 _Float16* __restrict__ Chi, _Float16* __restrict__ Clo,
                 const float* __restrict__ w3, float* __restrict__ part) {
  __shared__ _Float16 lds[3 * 8192];   // Ahi|Alo|W tiles, each [128][64] = 16KB -> 48KB

  const int tid  = threadIdx.x;
  const int lane = tid & 63;
  const int wave = tid >> 6;
  const int wr = wave >> 1, wc = wave & 1;

  // XCD-chunked bijective swizzle: 384 = 8 XCDs * 48; siblings sharing an
  // A-panel (same mb, nb=0..5) land on one XCD -> A+W slice is L2-resident.
  const int bid = blockIdx.x;
  const int idp = (bid & 7) * 48 + (bid >> 3);
  const int mb = idp / 6, nb = idp % 6;
  const int row0 = mb * 128, col0 = nb * 128;

  const int lr = lane & 15, lk = lane >> 4;
  const int xorv = (lr & 7) << 3;            // swizzle for fragment reads

  const int sr = lane >> 3;                  // staging: 0..7
  const int sc = (lane & 7) * 8;             // element col, step 8 (16B)

  f32x4 acc[4][4] = {};

  for (int kt = 0; kt < NH / 64; ++kt) {
    const int kb = kt * 64;
#pragma unroll
    for (int i = 0; i < 4; ++i) {
      const int chunk = i * 4 + wave;        // 0..15, 8 rows each
      const int r = chunk * 8 + sr;
      const size_t ga = (size_t)(row0 + r) * NH + kb + sc;
      const size_t gb = (size_t)(col0 + r) * NH + kb + sc;
      gll16(Ahi + ga, &lds[0 * 8192 + chunk * 512]);
      gll16(Alo + ga, &lds[1 * 8192 + chunk * 512]);
      gll16(W   + gb, &lds[2 * 8192 + chunk * 512]);
    }
    __syncthreads();

#pragma unroll
    for (int kk = 0; kk < 2; ++kk) {
      const int kl = (kk * 32 + lk * 8) ^ xorv;
      half8 ah[4], al[4], bw[4];
#pragma unroll
      for (int f = 0; f < 4; ++f) {
        const int ra = (wr * 64 + f * 16 + lr) * 64 + kl;
        ah[f] = *(const half8*)&lds[0 * 8192 + ra];
        al[f] = *(const half8*)&lds[1 * 8192 + ra];
        const int rb = (wc * 64 + f * 16 + lr) * 64 + kl;
        bw[f] = *(const half8*)&lds[2 * 8192 + rb];
      }
#pragma unroll
      for (int mf = 0; mf < 4; ++mf)
#pragma unroll
        for (int nf = 0; nf < 4; ++nf) {
          acc[mf][nf] = __builtin_amdgcn_mfma_f32_16x16x32_f16(ah[mf], bw[nf], acc[mf][nf], 0, 0, 0);
          acc[mf][nf] = __builtin_amdgcn_mfma_f32_16x16x32_f16(al[mf], bw[nf], acc[mf][nf], 0, 0, 0);
        }
    }
    __syncthreads();
  }

  // epilogue. C/D layout: col = lane&15, row = (lane>>4)*4 + reg  [m89-verified]
  if (EPI == 0) {
#pragma unroll
    for (int nf = 0; nf < 4; ++nf) {
      const int col = col0 + wc * 64 + nf * 16 + lr;
      const float bv = bias[col];
#pragma unroll
      for (int mf = 0; mf < 4; ++mf) {
#pragma unroll
        for (int r = 0; r < 4; ++r) {
          const int rowm = row0 + wr * 64 + mf * 16 + lk * 4 + r;
          float g = gelu_exact(acc[mf][nf][r] + bv);
          _Float16 h = (_Float16)g;
          _Float16 l = (_Float16)(g - (float)h);
          size_t off = (size_t)rowm * NH + (size_t)(col ^ ((rowm & 7) << 3));
          Chi[off] = h;
          Clo[off] = l;
        }
      }
    }
  } else {
    float bv[4], wv[4];
#pragma unroll
    for (int nf = 0; nf < 4; ++nf) {
      const int col = col0 + wc * 64 + nf * 16 + lr;
      bv[nf] = bias[col];
      wv[nf] = w3[col];
    }
#pragma unroll
    for (int mf = 0; mf < 4; ++mf) {
#pragma unroll
      for (int r = 0; r < 4; ++r) {
        float p = 0.f;
#pragma unroll
        for (int nf = 0; nf < 4; ++nf)
          p += gelu_exact(acc[mf][nf][r] + bv[nf]) * wv[nf];
        p += __shfl_xor(p, 1, 16);
        p += __shfl_xor(p, 2, 16);
        p += __shfl_xor(p, 4, 16);
        p += __shfl_xor(p, 8, 16);
        if (lr == 0) {
          const int rowm = row0 + wr * 64 + mf * 16 + lk * 4 + r;
          part[((size_t)(nb * 2 + wc)) * NM + rowm] = p;   // distinct slot per column-half
        }
      }
    }
  }
}

// ---------------------------------------------------------------------------
extern "C" void kernel_launch(void* const* d_in, const int* in_sizes, int n_in,
                              void* d_out, int out_size, void* d_ws, size_t ws_size,
                              hipStream_t stream) {
  (void)in_sizes; (void)n_in; (void)out_size; (void)ws_size;
  const float* hidden = (const float*)d_in[0];
  const int*   sid    = (const int*)d_in[1];
  const float* w1     = (const float*)d_in[2];
  const float* b1     = (const float*)d_in[3];
  const float* w2     = (const float*)d_in[4];
  const float* b2     = (const float*)d_in[5];
  const float* w3     = (const float*)d_in[6];
  const float* b3     = (const float*)d_in[7];
  float* out = (float*)d_out;

  char* p = (char*)d_ws;
  const size_t actE = (size_t)NM * NH;           // elements per activation buffer
  // pooled (f32, dead after convert) aliases X1hi+X1lo (written by GEMM0 later)
  float*    pooled = (float*)p;
  _Float16* X1hi   = (_Float16*)p; p += actE * 2;
  _Float16* X1lo   = (_Float16*)p; p += actE * 2;
  _Float16* Ahi    = (_Float16*)p; p += actE * 2;
  _Float16* Alo    = (_Float16*)p; p += actE * 2;
  _Float16* W      = (_Float16*)p; p += (size_t)2 * NH * NH * 2;
  float*    part   = (float*)p;    p += (size_t)12 * NM * 4;

  hipMemsetAsync(pooled, 0, actE * 4, stream);
  prep_w_kernel<<<2 * 96 * NH / 256, 256, 0, stream>>>(w1, w2, W);
  pool_sum_kernel<<<dim3(16, 64), 192, 0, stream>>>(hidden, sid, pooled);
  convert_kernel<<<NM, 192, 0, stream>>>(pooled, sid, Ahi, Alo);

  gemm_kernel<0><<<384, 256, 0, stream>>>(Ahi, Alo, W, b1, X1hi, X1lo, nullptr, nullptr);
  gemm_kernel<1><<<384, 256, 0, stream>>>(X1hi, X1lo, W + (size_t)NH * NH, b2,
                                          nullptr, nullptr, w3, part);
  finish_kernel<<<NM / 256, 256, 0, stream>>>(part, b3, out);
}

// Round 5
// 242.427 us; speedup vs baseline: 1.2709x; 1.2709x over previous
//
#include <hip/hip_runtime.h>
#include <stdint.h>

#define NB 64
#define NT 512
#define NH 768
#define NS 128
#define NM (NB*NS)   // 8192 rows

typedef _Float16 half8 __attribute__((ext_vector_type(8)));
typedef _Float16 half4 __attribute__((ext_vector_type(4)));
typedef __attribute__((ext_vector_type(4))) float f32x4;

__device__ __forceinline__ float gelu_exact(float x) {
  return 0.5f * x * (1.0f + erff(x * 0.70710678118654752440f));
}

// async global->LDS, 16B per lane; LDS dest is wave-uniform base (HW adds lane*16)
__device__ __forceinline__ void gll16(const void* g, void* l) {
  __builtin_amdgcn_global_load_lds(
      (__attribute__((address_space(1))) unsigned int*)g,
      (__attribute__((address_space(3))) unsigned int*)l,
      16, 0, 0);
}

// ---------------------------------------------------------------------------
// Weight prep: w[k][n] f32 -> W[w][n][k] f16, pre-swizzled (k ^ ((n&7)<<3))
// ---------------------------------------------------------------------------
__global__ void prep_w_kernel(const float* __restrict__ w1, const float* __restrict__ w2,
                              _Float16* __restrict__ W) {
  int id = blockIdx.x * 256 + threadIdx.x;   // 2*96*768 total
  int n  = id % NH;
  int t  = id / NH;
  int kc = t % 96;
  int w  = t / 96;
  const float* src = w ? w2 : w1;
  int k0 = kc * 8;
  half8 h;
#pragma unroll
  for (int i = 0; i < 8; ++i)
    h[i] = (_Float16)src[(size_t)(k0 + i) * NH + n];   // coalesced across n
  *(half8*)&W[(size_t)w * NH * NH + (size_t)n * NH + (size_t)(k0 ^ ((n & 7) << 3))] = h;
}

// ---------------------------------------------------------------------------
// Fused pool: segment-mean + f16 hi/lo split + swizzled store. NO atomics.
// grid (12 col-chunks, 64 batches), 256 threads = 16 seg-groups x 16 f32x4-cols.
// Segment boundary table built in LDS from the sorted sid row.
// ---------------------------------------------------------------------------
__global__ __launch_bounds__(256)
void pool_kernel(const float* __restrict__ hidden, const int* __restrict__ sid,
                 _Float16* __restrict__ Ahi, _Float16* __restrict__ Alo) {
  __shared__ int   s_sid[NT];
  __shared__ short s_e0[NS + 1];
  const int b = blockIdx.y, cc = blockIdx.x;
  const int tid = threadIdx.x;
  for (int t = tid; t < NT; t += 256) s_sid[t] = sid[b * NT + t];
  __syncthreads();
  for (int t = tid; t < NT; t += 256) {
    const int cur  = s_sid[t];
    const int prev = t ? s_sid[t - 1] : -1;
    for (int s = prev + 1; s <= cur; ++s) s_e0[s] = (short)t;   // each s written once
    if (t == NT - 1)
      for (int s = cur + 1; s <= NS; ++s) s_e0[s] = (short)NT;
  }
  __syncthreads();

  const int c4  = tid & 15;           // 16 f32x4 column groups -> 64 cols
  const int sg  = tid >> 4;           // 16 segment groups
  const int col = cc * 64 + c4 * 4;
  const float* hb = hidden + (size_t)b * NT * NH;

  for (int s = sg; s < NS; s += 16) { // 8 segments per thread, strided for balance
    const int e0 = s_e0[s], e1 = s_e0[s + 1];
    f32x4 acc = {0.f, 0.f, 0.f, 0.f};
    for (int t = e0; t < e1; ++t)
      acc += *(const f32x4*)(hb + (size_t)t * NH + col);
    const float inv = 1.0f / (float)((e1 > e0) ? (e1 - e0) : 1);
    const int m = b * NS + s;
    half4 h, l;
#pragma unroll
    for (int j = 0; j < 4; ++j) {
      float x = acc[j] * inv;
      h[j] = (_Float16)x;
      l[j] = (_Float16)(x - (float)h[j]);
    }
    // xor flips element bits 3..5 only: 4-aligned half4 stays contiguous
    const size_t off = (size_t)m * NH + (size_t)(col ^ ((m & 7) << 3));
    *(half4*)&Ahi[off] = h;
    *(half4*)&Alo[off] = l;
  }
}

__global__ void finish_kernel(const float* __restrict__ part, const float* __restrict__ b3,
                              float* __restrict__ out) {
  int i = blockIdx.x * 256 + threadIdx.x;
  float s = b3[0];
#pragma unroll
  for (int j = 0; j < 12; ++j) s += part[(size_t)j * NM + i];
  out[i] = 1.0f / (1.0f + expf(-s));
}

// ---------------------------------------------------------------------------
// f16x2 GEMM, 64x128 tile, BK=64, 4 waves (2 row x 2 col), 16x16x32 f16 MFMA.
// Grid 128*6 = 768 blocks = exactly 3/CU (balanced; 384-block version left
// half the CUs with 2 serial blocks).
// A: [M][768] swizzled f16 hi/lo.  W: [N][K] swizzled f16.
// EPI==0: C = gelu(A@W^T + bias) -> f16 hi/lo swizzled store
// EPI==1: per-row dot(gelu(..), w3) -> part[(nb*2+wc)][row]
// ---------------------------------------------------------------------------
template <int EPI>
__global__ __launch_bounds__(256, 3)
void gemm_kernel(const _Float16* __restrict__ Ahi, const _Float16* __restrict__ Alo,
                 const _Float16* __restrict__ W, const float* __restrict__ bias,
                 _Float16* __restrict__ Chi, _Float16* __restrict__ Clo,
                 const float* __restrict__ w3, float* __restrict__ part) {
  __shared__ _Float16 lds[16384];   // Ahi [0,4K) | Alo [4K,8K) | W [8K,16K) elems; 32 KB

  const int tid  = threadIdx.x;
  const int lane = tid & 63;
  const int wave = tid >> 6;
  const int wr = wave >> 1, wc = wave & 1;

  // XCD-chunked bijective swizzle: 768 = 8 XCDs * 96; the 6 nb-siblings of an
  // A-panel stay on one XCD -> W (1.2 MB) + A-slice L2-resident.
  const int bid = blockIdx.x;
  const int idp = (bid & 7) * 96 + (bid >> 3);
  const int mb = idp / 6, nb = idp % 6;
  const int row0 = mb * 64, col0 = nb * 128;

  const int lr = lane & 15, lk = lane >> 4;
  const int sr = lane >> 3;                  // staging row within 8-row chunk
  const int scol = (lane & 7) * 8;           // staging col, 8 elems = 16B

  f32x4 acc[2][4] = {};

  for (int kt = 0; kt < NH / 64; ++kt) {
    const int kb = kt * 64;
#pragma unroll
    for (int i = 0; i < 8; ++i) {
      const int cid = i * 4 + wave;          // 0..31 chunks of 8 rows
      if (cid < 16) {                        // A hi/lo
        const int arr = cid >> 3;
        const int r = (cid & 7) * 8 + sr;
        const size_t g = (size_t)(row0 + r) * NH + kb + scol;
        gll16((arr ? Alo : Ahi) + g, &lds[arr * 4096 + (cid & 7) * 512]);
      } else {                               // W
        const int r = (cid - 16) * 8 + sr;
        gll16(W + (size_t)(col0 + r) * NH + kb + scol, &lds[8192 + (cid - 16) * 512]);
      }
    }
    __syncthreads();

#pragma unroll
    for (int kk = 0; kk < 2; ++kk) {
      const int kl = kk * 32 + lk * 8;
      half8 ah[2], al[2], bw[4];
#pragma unroll
      for (int mf = 0; mf < 2; ++mf) {
        const int ar = wr * 32 + mf * 16 + lr;
        const int ad = ar * 64 + (kl ^ ((ar & 7) << 3));
        ah[mf] = *(const half8*)&lds[ad];
        al[mf] = *(const half8*)&lds[4096 + ad];
      }
#pragma unroll
      for (int nf = 0; nf < 4; ++nf) {
        const int br = wc * 64 + nf * 16 + lr;
        bw[nf] = *(const half8*)&lds[8192 + br * 64 + (kl ^ ((br & 7) << 3))];
      }
#pragma unroll
      for (int mf = 0; mf < 2; ++mf)
#pragma unroll
        for (int nf = 0; nf < 4; ++nf) {
          acc[mf][nf] = __builtin_amdgcn_mfma_f32_16x16x32_f16(ah[mf], bw[nf], acc[mf][nf], 0, 0, 0);
          acc[mf][nf] = __builtin_amdgcn_mfma_f32_16x16x32_f16(al[mf], bw[nf], acc[mf][nf], 0, 0, 0);
        }
    }
    __syncthreads();
  }

  // epilogue. C/D layout: col = lane&15, row = (lane>>4)*4 + reg  [m89-verified]
  if (EPI == 0) {
#pragma unroll
    for (int nf = 0; nf < 4; ++nf) {
      const int col = col0 + wc * 64 + nf * 16 + lr;
      const float bv = bias[col];
#pragma unroll
      for (int mf = 0; mf < 2; ++mf) {
#pragma unroll
        for (int r = 0; r < 4; ++r) {
          const int rowm = row0 + wr * 32 + mf * 16 + lk * 4 + r;
          float g = gelu_exact(acc[mf][nf][r] + bv);
          _Float16 h = (_Float16)g;
          _Float16 l = (_Float16)(g - (float)h);
          size_t off = (size_t)rowm * NH + (size_t)(col ^ ((rowm & 7) << 3));
          Chi[off] = h;
          Clo[off] = l;
        }
      }
    }
  } else {
    float bv[4], wv[4];
#pragma unroll
    for (int nf = 0; nf < 4; ++nf) {
      const int col = col0 + wc * 64 + nf * 16 + lr;
      bv[nf] = bias[col];
      wv[nf] = w3[col];
    }
#pragma unroll
    for (int mf = 0; mf < 2; ++mf) {
#pragma unroll
      for (int r = 0; r < 4; ++r) {
        float p = 0.f;
#pragma unroll
        for (int nf = 0; nf < 4; ++nf)
          p += gelu_exact(acc[mf][nf][r] + bv[nf]) * wv[nf];
        p += __shfl_xor(p, 1, 16);
        p += __shfl_xor(p, 2, 16);
        p += __shfl_xor(p, 4, 16);
        p += __shfl_xor(p, 8, 16);
        if (lr == 0) {
          const int rowm = row0 + wr * 32 + mf * 16 + lk * 4 + r;
          part[((size_t)(nb * 2 + wc)) * NM + rowm] = p;   // distinct slot per column-half
        }
      }
    }
  }
}

// ---------------------------------------------------------------------------
extern "C" void kernel_launch(void* const* d_in, const int* in_sizes, int n_in,
                              void* d_out, int out_size, void* d_ws, size_t ws_size,
                              hipStream_t stream) {
  (void)in_sizes; (void)n_in; (void)out_size; (void)ws_size;
  const float* hidden = (const float*)d_in[0];
  const int*   sid    = (const int*)d_in[1];
  const float* w1     = (const float*)d_in[2];
  const float* b1     = (const float*)d_in[3];
  const float* w2     = (const float*)d_in[4];
  const float* b2     = (const float*)d_in[5];
  const float* w3     = (const float*)d_in[6];
  const float* b3     = (const float*)d_in[7];
  float* out = (float*)d_out;

  char* p = (char*)d_ws;
  const size_t actE = (size_t)NM * NH;
  _Float16* Ahi  = (_Float16*)p; p += actE * 2;
  _Float16* Alo  = (_Float16*)p; p += actE * 2;
  _Float16* X1hi = (_Float16*)p; p += actE * 2;
  _Float16* X1lo = (_Float16*)p; p += actE * 2;
  _Float16* W    = (_Float16*)p; p += (size_t)2 * NH * NH * 2;
  float*    part = (float*)p;    p += (size_t)12 * NM * 4;

  prep_w_kernel<<<2 * 96 * NH / 256, 256, 0, stream>>>(w1, w2, W);
  pool_kernel<<<dim3(12, NB), 256, 0, stream>>>(hidden, sid, Ahi, Alo);

  gemm_kernel<0><<<768, 256, 0, stream>>>(Ahi, Alo, W, b1, X1hi, X1lo, nullptr, nullptr);
  gemm_kernel<1><<<768, 256, 0, stream>>>(X1hi, X1lo, W + (size_t)NH * NH, b2,
                                          nullptr, nullptr, w3, part);
  finish_kernel<<<NM / 256, 256, 0, stream>>>(part, b3, out);
}